// Round 5
// baseline (906.323 us; speedup 1.0000x reference)
//
#include <hip/hip_runtime.h>

#define N_NODES 20000
#define N_EDGES 320000
#define DIM 256
#define H_HEADS 4

typedef _Float16 f16x8 __attribute__((ext_vector_type(8)));
typedef _Float16 f16x4 __attribute__((ext_vector_type(4)));
typedef float f32x4v __attribute__((ext_vector_type(4)));

// ---------------- init: convert W to f16 transposed + edge histogram ----------------
__global__ void k_init_hist(const float* __restrict__ Wn, const float* __restrict__ We,
                            _Float16* __restrict__ WTn, _Float16* __restrict__ WTe,
                            const int* __restrict__ dst, unsigned int* __restrict__ counts)
{
    int i = blockIdx.x * 256 + threadIdx.x;
    if (i < DIM * DIM) {
        int n = i >> 8, k = i & 255;
        WTn[i] = (_Float16)Wn[k * DIM + n];
        WTe[i] = (_Float16)We[k * DIM + n];
    }
    if (i < N_EDGES) atomicAdd(&counts[dst[i]], 1u);
}

// single-pass chunked scan: 1024 threads x 20 elements, one shuffle-scan, 2 barriers
__global__ __launch_bounds__(1024) void k_scan(unsigned int* __restrict__ counts,
                                               unsigned int* __restrict__ cursor)
{
    __shared__ unsigned int wsum[16];
    const int t = threadIdx.x, lane = t & 63, wv = t >> 6;
    const int CH = 20;                       // 1024*20 = 20480 >= 20001
    unsigned int v[CH];
    const int base = t * CH;
    unsigned int sum = 0;
#pragma unroll
    for (int i = 0; i < CH; ++i) {
        int idx = base + i;
        v[i] = (idx < N_NODES) ? counts[idx] : 0u;
        sum += v[i];
    }
    unsigned int x = sum;
#pragma unroll
    for (int off = 1; off < 64; off <<= 1) {
        unsigned int y = __shfl_up(x, off);
        if (lane >= off) x += y;
    }
    if (lane == 63) wsum[wv] = x;
    __syncthreads();
    if (t < 16) {
        unsigned int s = wsum[t];
#pragma unroll
        for (int off = 1; off < 16; off <<= 1) {
            unsigned int y = __shfl_up(s, off);
            if (t >= off) s += y;
        }
        wsum[t] = s;                          // inclusive scan of wave sums
    }
    __syncthreads();
    unsigned int run = (wv ? wsum[wv - 1] : 0u) + x - sum;   // exclusive base
#pragma unroll
    for (int i = 0; i < CH; ++i) {
        int idx = base + i;
        if (idx < N_NODES) { counts[idx] = run; cursor[idx] = run; }
        run += v[i];
    }
    if (t == 1023) counts[N_NODES] = run;     // = N_EDGES
}

__global__ void k_scatter(const int* __restrict__ dst, unsigned int* __restrict__ cursor,
                          int* __restrict__ esort)
{
    int i = blockIdx.x * 256 + threadIdx.x;
    if (i < N_EDGES) {
        unsigned int p = atomicAdd(&cursor[dst[i]], 1u);
        esort[p] = i;
    }
}

// ---------------- node projection GEMM: ft = nfeat @ W_node (f32 out) ----------------
// MFMA operand-swapped: acc = mfma(Wfrag, Afrag) -> lane holds row=c16 (node),
// 4 consecutive cols per reg group -> float4 C stores.
__global__ __launch_bounds__(256) void k_gemm_node(
    const float* __restrict__ A, const _Float16* __restrict__ WT,
    float* __restrict__ C, int M)
{
    __shared__ __align__(16) _Float16 Alds[64][40];
    const int t = threadIdx.x;
    const int m0 = blockIdx.x * 64;
    const int lane = t & 63, w = t >> 6;
    const int q = lane >> 4, c16 = lane & 15;
    const int srow = t >> 2;
    const int skb = (t & 3) * 8;
    f32x4v acc[4][4] = {};

    const int grow = m0 + srow;
    const bool valid = grow < M;
    const float* gp = A + (size_t)grow * DIM + skb;
    f32x4v p0[2] = {}, p1[2] = {};
    if (valid) {
        p0[0] = __builtin_nontemporal_load((const f32x4v*)gp);
        p1[0] = __builtin_nontemporal_load((const f32x4v*)(gp + 4));
        p0[1] = __builtin_nontemporal_load((const f32x4v*)(gp + 32));
        p1[1] = __builtin_nontemporal_load((const f32x4v*)(gp + 36));
    }

#pragma unroll
    for (int s = 0; s < 8; ++s) {
        const int k0 = s * 32;
        const int b = s & 1;
        f16x8 h8;
        h8[0]=(_Float16)p0[b][0]; h8[1]=(_Float16)p0[b][1]; h8[2]=(_Float16)p0[b][2]; h8[3]=(_Float16)p0[b][3];
        h8[4]=(_Float16)p1[b][0]; h8[5]=(_Float16)p1[b][1]; h8[6]=(_Float16)p1[b][2]; h8[7]=(_Float16)p1[b][3];
        __syncthreads();
        *(f16x8*)&Alds[srow][skb] = h8;
        __syncthreads();
        if (s < 6 && valid) {
            p0[b] = __builtin_nontemporal_load((const f32x4v*)(gp + k0 + 64));
            p1[b] = __builtin_nontemporal_load((const f32x4v*)(gp + k0 + 68));
        }

        f16x8 bfr[4], afr[4];
#pragma unroll
        for (int ni = 0; ni < 4; ++ni) {
            int col = (w << 6) + (ni << 4) + c16;
            bfr[ni] = *(const f16x8*)(WT + (size_t)col * DIM + k0 + q * 8);
        }
#pragma unroll
        for (int mi = 0; mi < 4; ++mi)
            afr[mi] = *(const f16x8*)&Alds[c16 + 16 * mi][q * 8];
#pragma unroll
        for (int mi = 0; mi < 4; ++mi)
#pragma unroll
            for (int ni = 0; ni < 4; ++ni)
                acc[mi][ni] = __builtin_amdgcn_mfma_f32_16x16x32_f16(bfr[ni], afr[mi], acc[mi][ni], 0, 0, 0);
    }

    // epilogue: lane owns node row m0+16mi+c16, cols w*64+ni*16+q*4 .. +3 (float4)
#pragma unroll
    for (int mi = 0; mi < 4; ++mi) {
        int row = m0 + (mi << 4) + c16;
        if (row < M) {
#pragma unroll
            for (int ni = 0; ni < 4; ++ni) {
                int c = (w << 6) + (ni << 4) + (q << 2);
                *(f32x4v*)(C + (size_t)row * DIM + c) = acc[mi][ni];
            }
        }
    }
}

// ---------------- fused edge GEMM, barrier-free: each wave owns 16 edges x 256 cols ----------------
// No LDS, no __syncthreads. A-fragments straight from global (coalesced 128B/row/k-step),
// B-fragments (WT, 128KB) from L2. acc[ni]: edge row = c16, col = ni*16 + q*4 + reg.
__global__ __launch_bounds__(256) void k_gemm_edge(
    const float* __restrict__ efeat, const _Float16* __restrict__ WT,
    const float* __restrict__ ft, const int* __restrict__ src, const int* __restrict__ dst,
    const int* __restrict__ esort,
    _Float16* __restrict__ ftp, float* __restrict__ a_ws)
{
    const int t = threadIdx.x;
    const int lane = t & 63;
    const int q = lane >> 4, c16 = lane & 15;
    const int e = blockIdx.x * 64 + (t >> 6) * 16 + c16;   // this lane's edge (sorted pos)

    const int eidx = esort[e];
    const int se = src[eidx];
    const int de = dst[eidx];

    const float* gp = efeat + (size_t)eidx * DIM + q * 8;
    f32x4v acc[16] = {};

#pragma unroll
    for (int s = 0; s < 8; ++s) {
        const int k0 = s * 32;
        f32x4v v0 = __builtin_nontemporal_load((const f32x4v*)(gp + k0));
        f32x4v v1 = __builtin_nontemporal_load((const f32x4v*)(gp + k0 + 4));
        f16x8 afr;
        afr[0]=(_Float16)v0[0]; afr[1]=(_Float16)v0[1]; afr[2]=(_Float16)v0[2]; afr[3]=(_Float16)v0[3];
        afr[4]=(_Float16)v1[0]; afr[5]=(_Float16)v1[1]; afr[6]=(_Float16)v1[2]; afr[7]=(_Float16)v1[3];
#pragma unroll
        for (int ni = 0; ni < 16; ++ni) {
            f16x8 bfr = *(const f16x8*)(WT + (size_t)((ni << 4) + c16) * DIM + k0 + q * 8);
            acc[ni] = __builtin_amdgcn_mfma_f32_16x16x32_f16(bfr, afr, acc[ni], 0, 0, 0);
        }
    }

    // epilogue: lane owns edge e, cols ni*16 + q*4 .. +3. head(col) = ni>>2 (lane-local).
    const float* fsrc = ft + (size_t)se * DIM;
    const float* fdst = ft + (size_t)de * DIM;
    float dots[4] = {};
#pragma unroll
    for (int ni = 0; ni < 16; ++ni) {
        const int c = (ni << 4) + (q << 2);
        f32x4v fs = *(const f32x4v*)(fsrc + c);
        f32x4v fd = *(const f32x4v*)(fdst + c);
        f32x4v v = acc[ni] + fs;
        f16x4 h;
        h[0] = (_Float16)v[0]; h[1] = (_Float16)v[1];
        h[2] = (_Float16)v[2]; h[3] = (_Float16)v[3];
        *(f16x4*)(ftp + (size_t)e * DIM + c) = h;
        dots[ni >> 2] += v[0]*fd[0] + v[1]*fd[1] + v[2]*fd[2] + v[3]*fd[3];
    }
#pragma unroll
    for (int h = 0; h < 4; ++h) {
        dots[h] += __shfl_xor(dots[h], 16);
        dots[h] += __shfl_xor(dots[h], 32);
    }
    a_ws[e * H_HEADS + q] = dots[q];
}

// ---------------- fused softmax + aggregation: one wave per node, 4 edges/iter ----------------
__global__ __launch_bounds__(256) void k_agg(
    const unsigned int* __restrict__ offs, const float* __restrict__ a_ws,
    const _Float16* __restrict__ ftp, float* __restrict__ out)
{
    const int n = blockIdx.x * 4 + (threadIdx.x >> 6);
    const int lane = threadIdx.x & 63;
    const int beg = (int)offs[n], end = (int)offs[n + 1];

    // pass A: per-head max (lane's elements all have head lane&3)
    float m = -1e30f;
    for (int j = beg * 4 + lane; j < end * 4; j += 64)
        m = fmaxf(m, a_ws[j]);
    m = fmaxf(m, __shfl_xor(m, 4));
    m = fmaxf(m, __shfl_xor(m, 8));
    m = fmaxf(m, __shfl_xor(m, 16));
    m = fmaxf(m, __shfl_xor(m, 32));

    // pass B: per-head sum of exp
    float sm = 0.f;
    for (int j = beg * 4 + lane; j < end * 4; j += 64)
        sm += __expf(a_ws[j] - m);
    sm += __shfl_xor(sm, 4);
    sm += __shfl_xor(sm, 8);
    sm += __shfl_xor(sm, 16);
    sm += __shfl_xor(sm, 32);

    // pass C: 4 edges per iteration, 16 lanes per edge, 32 B per lane
    const int quarter = lane >> 4;       // which of 4 edges
    const int cl = lane & 15;
    const int cb = cl * 16;              // col base (16 f16 per lane)
    const int hc = cl >> 2;              // head of these cols
    const float mh = __shfl(m, hc);
    const float sh = __shfl(sm, hc);
    const float inv = (end > beg) ? 0.125f / sh : 0.f;

    float acc[16] = {};
    for (int j = beg + quarter; j < end; j += 4) {
        float wj = __expf(a_ws[j * H_HEADS + hc] - mh);
        const _Float16* fp = ftp + (size_t)j * DIM + cb;
        f16x8 d0 = *(const f16x8*)fp;
        f16x8 d1 = *(const f16x8*)(fp + 8);
#pragma unroll
        for (int k = 0; k < 8; ++k) {
            acc[k]     += wj * (float)d0[k];
            acc[k + 8] += wj * (float)d1[k];
        }
    }
#pragma unroll
    for (int k = 0; k < 16; ++k) {
        acc[k] += __shfl_xor(acc[k], 16);
        acc[k] += __shfl_xor(acc[k], 32);
    }

    if (quarter == 0) {
        float* op = out + (size_t)n * DIM + cb;
#pragma unroll
        for (int v4 = 0; v4 < 4; ++v4) {
            float4 o = make_float4(acc[v4*4+0] * inv, acc[v4*4+1] * inv,
                                   acc[v4*4+2] * inv, acc[v4*4+3] * inv);
            *(float4*)(op + v4 * 4) = o;
        }
    }
}

// ---------------- launch ----------------
extern "C" void kernel_launch(void* const* d_in, const int* in_sizes, int n_in,
                              void* d_out, int out_size, void* d_ws, size_t ws_size,
                              hipStream_t stream)
{
    const float* nfeat = (const float*)d_in[0];
    const float* efeat = (const float*)d_in[1];
    const int* src = (const int*)d_in[2];
    const int* dst = (const int*)d_in[3];
    const float* Wn = (const float*)d_in[4];
    const float* We = (const float*)d_in[5];
    float* out = (float*)d_out;

    char* ws = (char*)d_ws;
    size_t off = 0;
    auto alloc = [&](size_t bytes) -> void* {
        off = (off + 255) & ~(size_t)255;
        void* p = ws + off;
        off += bytes;
        return p;
    };

    _Float16* WTn = (_Float16*)alloc((size_t)DIM * DIM * 2);
    _Float16* WTe = (_Float16*)alloc((size_t)DIM * DIM * 2);
    float* ft = (float*)alloc((size_t)N_NODES * DIM * 4);
    _Float16* ftp = (_Float16*)alloc((size_t)N_EDGES * DIM * 2);
    float* a_ws = (float*)alloc((size_t)N_EDGES * H_HEADS * 4);
    unsigned int* counts = (unsigned int*)alloc((size_t)(N_NODES + 1) * 4);
    unsigned int* cursor = (unsigned int*)alloc((size_t)N_NODES * 4);
    int* esort = (int*)alloc((size_t)N_EDGES * 4);

    hipMemsetAsync(counts, 0, (size_t)(N_NODES + 1) * 4, stream);
    k_init_hist<<<(N_EDGES + 255) / 256, 256, 0, stream>>>(Wn, We, WTn, WTe, dst, counts);
    k_scan<<<1, 1024, 0, stream>>>(counts, cursor);
    k_scatter<<<(N_EDGES + 255) / 256, 256, 0, stream>>>(dst, cursor, esort);
    k_gemm_node<<<(N_NODES + 63) / 64, 256, 0, stream>>>(nfeat, WTn, ft, N_NODES);
    k_gemm_edge<<<N_EDGES / 64, 256, 0, stream>>>(efeat, WTe, ft, src, dst, esort, ftp, a_ws);
    k_agg<<<N_NODES / 4, 256, 0, stream>>>(counts, a_ws, ftp, out);
}

// Round 6
// 683.106 us; speedup vs baseline: 1.3268x; 1.3268x over previous
//
#include <hip/hip_runtime.h>

#define N_NODES 20000
#define N_EDGES 320000
#define DIM 256
#define H_HEADS 4

typedef _Float16 f16x8 __attribute__((ext_vector_type(8)));
typedef _Float16 f16x4 __attribute__((ext_vector_type(4)));
typedef float f32x4v __attribute__((ext_vector_type(4)));

// ---------------- init: convert W to f16 transposed + edge histogram ----------------
__global__ void k_init_hist(const float* __restrict__ Wn, const float* __restrict__ We,
                            _Float16* __restrict__ WTn, _Float16* __restrict__ WTe,
                            const int* __restrict__ dst, unsigned int* __restrict__ counts)
{
    int i = blockIdx.x * 256 + threadIdx.x;
    if (i < DIM * DIM) {
        int n = i >> 8, k = i & 255;
        WTn[i] = (_Float16)Wn[k * DIM + n];
        WTe[i] = (_Float16)We[k * DIM + n];
    }
    if (i < N_EDGES) atomicAdd(&counts[dst[i]], 1u);
}

// single-pass chunked scan: 1024 threads x 20 elements, one shuffle-scan, 2 barriers
__global__ __launch_bounds__(1024) void k_scan(unsigned int* __restrict__ counts,
                                               unsigned int* __restrict__ cursor)
{
    __shared__ unsigned int wsum[16];
    const int t = threadIdx.x, lane = t & 63, wv = t >> 6;
    const int CH = 20;                       // 1024*20 = 20480 >= 20001
    unsigned int v[CH];
    const int base = t * CH;
    unsigned int sum = 0;
#pragma unroll
    for (int i = 0; i < CH; ++i) {
        int idx = base + i;
        v[i] = (idx < N_NODES) ? counts[idx] : 0u;
        sum += v[i];
    }
    unsigned int x = sum;
#pragma unroll
    for (int off = 1; off < 64; off <<= 1) {
        unsigned int y = __shfl_up(x, off);
        if (lane >= off) x += y;
    }
    if (lane == 63) wsum[wv] = x;
    __syncthreads();
    if (t < 16) {
        unsigned int s = wsum[t];
#pragma unroll
        for (int off = 1; off < 16; off <<= 1) {
            unsigned int y = __shfl_up(s, off);
            if (t >= off) s += y;
        }
        wsum[t] = s;                          // inclusive scan of wave sums
    }
    __syncthreads();
    unsigned int run = (wv ? wsum[wv - 1] : 0u) + x - sum;   // exclusive base
#pragma unroll
    for (int i = 0; i < CH; ++i) {
        int idx = base + i;
        if (idx < N_NODES) { counts[idx] = run; cursor[idx] = run; }
        run += v[i];
    }
    if (t == 1023) counts[N_NODES] = run;     // = N_EDGES
}

__global__ void k_scatter(const int* __restrict__ dst, unsigned int* __restrict__ cursor,
                          int* __restrict__ esort)
{
    int i = blockIdx.x * 256 + threadIdx.x;
    if (i < N_EDGES) {
        unsigned int p = atomicAdd(&cursor[dst[i]], 1u);
        esort[p] = i;
    }
}

// ---------------- node projection GEMM: ft = nfeat @ W_node (f32 out) ----------------
// MFMA operand-swapped: acc = mfma(Wfrag, Afrag) -> lane holds row=c16 (node),
// 4 consecutive cols per reg group -> float4 C stores.
__global__ __launch_bounds__(256) void k_gemm_node(
    const float* __restrict__ A, const _Float16* __restrict__ WT,
    float* __restrict__ C, int M)
{
    __shared__ __align__(16) _Float16 Alds[64][40];
    const int t = threadIdx.x;
    const int m0 = blockIdx.x * 64;
    const int lane = t & 63, w = t >> 6;
    const int q = lane >> 4, c16 = lane & 15;
    const int srow = t >> 2;
    const int skb = (t & 3) * 8;
    f32x4v acc[4][4] = {};

    const int grow = m0 + srow;
    const bool valid = grow < M;
    const float* gp = A + (size_t)grow * DIM + skb;
    f32x4v p0[2] = {}, p1[2] = {};
    if (valid) {
        p0[0] = __builtin_nontemporal_load((const f32x4v*)gp);
        p1[0] = __builtin_nontemporal_load((const f32x4v*)(gp + 4));
        p0[1] = __builtin_nontemporal_load((const f32x4v*)(gp + 32));
        p1[1] = __builtin_nontemporal_load((const f32x4v*)(gp + 36));
    }

#pragma unroll
    for (int s = 0; s < 8; ++s) {
        const int k0 = s * 32;
        const int b = s & 1;
        f16x8 h8;
        h8[0]=(_Float16)p0[b][0]; h8[1]=(_Float16)p0[b][1]; h8[2]=(_Float16)p0[b][2]; h8[3]=(_Float16)p0[b][3];
        h8[4]=(_Float16)p1[b][0]; h8[5]=(_Float16)p1[b][1]; h8[6]=(_Float16)p1[b][2]; h8[7]=(_Float16)p1[b][3];
        __syncthreads();
        *(f16x8*)&Alds[srow][skb] = h8;
        __syncthreads();
        if (s < 6 && valid) {
            p0[b] = __builtin_nontemporal_load((const f32x4v*)(gp + k0 + 64));
            p1[b] = __builtin_nontemporal_load((const f32x4v*)(gp + k0 + 68));
        }

        f16x8 bfr[4], afr[4];
#pragma unroll
        for (int ni = 0; ni < 4; ++ni) {
            int col = (w << 6) + (ni << 4) + c16;
            bfr[ni] = *(const f16x8*)(WT + (size_t)col * DIM + k0 + q * 8);
        }
#pragma unroll
        for (int mi = 0; mi < 4; ++mi)
            afr[mi] = *(const f16x8*)&Alds[c16 + 16 * mi][q * 8];
#pragma unroll
        for (int mi = 0; mi < 4; ++mi)
#pragma unroll
            for (int ni = 0; ni < 4; ++ni)
                acc[mi][ni] = __builtin_amdgcn_mfma_f32_16x16x32_f16(bfr[ni], afr[mi], acc[mi][ni], 0, 0, 0);
    }

    // epilogue: lane owns node row m0+16mi+c16, cols w*64+ni*16+q*4 .. +3 (float4)
#pragma unroll
    for (int mi = 0; mi < 4; ++mi) {
        int row = m0 + (mi << 4) + c16;
        if (row < M) {
#pragma unroll
            for (int ni = 0; ni < 4; ++ni) {
                int c = (w << 6) + (ni << 4) + (q << 2);
                *(f32x4v*)(C + (size_t)row * DIM + c) = acc[mi][ni];
            }
        }
    }
}

// ---------------- fused edge GEMM, 8 waves x 32 cols: higher occupancy ----------------
// Block tile 64 edges x 256 cols, LDS-staged A (f16), swapped-operand MFMA.
// acc = 4x2 f32x4 = 32 AGPR/lane -> ~115 regs -> 4 waves/SIMD (vs 3 at 64-col waves).
__global__ __launch_bounds__(512) void k_gemm_edge(
    const float* __restrict__ efeat, const _Float16* __restrict__ WT,
    const float* __restrict__ ft, const int* __restrict__ src, const int* __restrict__ dst,
    const int* __restrict__ esort,
    _Float16* __restrict__ ftp, float* __restrict__ a_ws)
{
    __shared__ __align__(16) _Float16 Alds[64][40];
    __shared__ int eidx[64], ssrc[64], sdst[64];
    __shared__ float apart[64][8];
    const int t = threadIdx.x;
    const int e0 = blockIdx.x * 64;
    const int lane = t & 63, w = t >> 6;       // w in 0..7, 32 cols each
    const int q = lane >> 4, c16 = lane & 15;
    const int srow = t >> 3;                   // staging row 0..63 (8 thr/row)
    const int skq = (t & 7) * 4;               // staging col (f32) 0..28
    f32x4v acc[4][2] = {};

    if (t < 64) {
        int e = esort[e0 + t];
        eidx[t] = e;
        ssrc[t] = src[e];
        sdst[t] = dst[e];
    }
    __syncthreads();

    const float* gp = efeat + (size_t)eidx[srow] * DIM + skq;
    f32x4v p[2];                               // depth-2 prefetch (16 B/thread/step)
    p[0] = __builtin_nontemporal_load((const f32x4v*)gp);
    p[1] = __builtin_nontemporal_load((const f32x4v*)(gp + 32));

#pragma unroll
    for (int s = 0; s < 8; ++s) {
        const int k0 = s * 32;
        const int b = s & 1;
        f16x4 h4;
        h4[0]=(_Float16)p[b][0]; h4[1]=(_Float16)p[b][1];
        h4[2]=(_Float16)p[b][2]; h4[3]=(_Float16)p[b][3];
        __syncthreads();
        *(f16x4*)&Alds[srow][skq] = h4;
        __syncthreads();
        if (s < 6)
            p[b] = __builtin_nontemporal_load((const f32x4v*)(gp + k0 + 64));

        f16x8 bfr[2], afr[4];
#pragma unroll
        for (int ni = 0; ni < 2; ++ni) {
            int col = (w << 5) + (ni << 4) + c16;
            bfr[ni] = *(const f16x8*)(WT + (size_t)col * DIM + k0 + q * 8);
        }
#pragma unroll
        for (int mi = 0; mi < 4; ++mi)
            afr[mi] = *(const f16x8*)&Alds[c16 + 16 * mi][q * 8];
#pragma unroll
        for (int mi = 0; mi < 4; ++mi)
#pragma unroll
            for (int ni = 0; ni < 2; ++ni)
                acc[mi][ni] = __builtin_amdgcn_mfma_f32_16x16x32_f16(bfr[ni], afr[mi], acc[mi][ni], 0, 0, 0);
    }

    // epilogue: lane owns edge r=16mi+c16, cols w*32+ni*16+q*4..+3.
    // head of wave w's cols = w>>1 (uniform): partial dot per wave, combine pairs via LDS.
#pragma unroll
    for (int mi = 0; mi < 4; ++mi) {
        const int r = (mi << 4) + c16;
        const int e = e0 + r;
        const float* fsrc = ft + (size_t)ssrc[r] * DIM;
        const float* fdst = ft + (size_t)sdst[r] * DIM;
        float dotp = 0.f;
#pragma unroll
        for (int ni = 0; ni < 2; ++ni) {
            const int c = (w << 5) + (ni << 4) + (q << 2);
            f32x4v fs = *(const f32x4v*)(fsrc + c);
            f32x4v fd = *(const f32x4v*)(fdst + c);
            f32x4v v = acc[mi][ni] + fs;
            f16x4 h;
            h[0] = (_Float16)v[0]; h[1] = (_Float16)v[1];
            h[2] = (_Float16)v[2]; h[3] = (_Float16)v[3];
            *(f16x4*)(ftp + (size_t)e * DIM + c) = h;
            dotp += v[0]*fd[0] + v[1]*fd[1] + v[2]*fd[2] + v[3]*fd[3];
        }
        dotp += __shfl_xor(dotp, 16);
        dotp += __shfl_xor(dotp, 32);
        if (lane < 16) apart[r][w] = dotp;     // q == 0
    }
    __syncthreads();
    if (t < 256) {
        const int r = t >> 2, h = t & 3;
        a_ws[(e0 + r) * H_HEADS + h] = apart[r][2 * h] + apart[r][2 * h + 1];
    }
}

// ---------------- fused softmax + aggregation: one wave per node, 4 edges/iter ----------------
__global__ __launch_bounds__(256) void k_agg(
    const unsigned int* __restrict__ offs, const float* __restrict__ a_ws,
    const _Float16* __restrict__ ftp, float* __restrict__ out)
{
    const int n = blockIdx.x * 4 + (threadIdx.x >> 6);
    const int lane = threadIdx.x & 63;
    const int beg = (int)offs[n], end = (int)offs[n + 1];

    // pass A: per-head max (lane's elements all have head lane&3)
    float m = -1e30f;
    for (int j = beg * 4 + lane; j < end * 4; j += 64)
        m = fmaxf(m, a_ws[j]);
    m = fmaxf(m, __shfl_xor(m, 4));
    m = fmaxf(m, __shfl_xor(m, 8));
    m = fmaxf(m, __shfl_xor(m, 16));
    m = fmaxf(m, __shfl_xor(m, 32));

    // pass B: per-head sum of exp
    float sm = 0.f;
    for (int j = beg * 4 + lane; j < end * 4; j += 64)
        sm += __expf(a_ws[j] - m);
    sm += __shfl_xor(sm, 4);
    sm += __shfl_xor(sm, 8);
    sm += __shfl_xor(sm, 16);
    sm += __shfl_xor(sm, 32);

    // pass C: 4 edges per iteration, 16 lanes per edge, 32 B per lane
    const int quarter = lane >> 4;       // which of 4 edges
    const int cl = lane & 15;
    const int cb = cl * 16;              // col base (16 f16 per lane)
    const int hc = cl >> 2;              // head of these cols
    const float mh = __shfl(m, hc);
    const float sh = __shfl(sm, hc);
    const float inv = (end > beg) ? 0.125f / sh : 0.f;

    float acc[16] = {};
    for (int j = beg + quarter; j < end; j += 4) {
        float wj = __expf(a_ws[j * H_HEADS + hc] - mh);
        const _Float16* fp = ftp + (size_t)j * DIM + cb;
        f16x8 d0 = *(const f16x8*)fp;
        f16x8 d1 = *(const f16x8*)(fp + 8);
#pragma unroll
        for (int k = 0; k < 8; ++k) {
            acc[k]     += wj * (float)d0[k];
            acc[k + 8] += wj * (float)d1[k];
        }
    }
#pragma unroll
    for (int k = 0; k < 16; ++k) {
        acc[k] += __shfl_xor(acc[k], 16);
        acc[k] += __shfl_xor(acc[k], 32);
    }

    if (quarter == 0) {
        float* op = out + (size_t)n * DIM + cb;
#pragma unroll
        for (int v4 = 0; v4 < 4; ++v4) {
            float4 o = make_float4(acc[v4*4+0] * inv, acc[v4*4+1] * inv,
                                   acc[v4*4+2] * inv, acc[v4*4+3] * inv);
            *(float4*)(op + v4 * 4) = o;
        }
    }
}

// ---------------- launch ----------------
extern "C" void kernel_launch(void* const* d_in, const int* in_sizes, int n_in,
                              void* d_out, int out_size, void* d_ws, size_t ws_size,
                              hipStream_t stream)
{
    const float* nfeat = (const float*)d_in[0];
    const float* efeat = (const float*)d_in[1];
    const int* src = (const int*)d_in[2];
    const int* dst = (const int*)d_in[3];
    const float* Wn = (const float*)d_in[4];
    const float* We = (const float*)d_in[5];
    float* out = (float*)d_out;

    char* ws = (char*)d_ws;
    size_t off = 0;
    auto alloc = [&](size_t bytes) -> void* {
        off = (off + 255) & ~(size_t)255;
        void* p = ws + off;
        off += bytes;
        return p;
    };

    _Float16* WTn = (_Float16*)alloc((size_t)DIM * DIM * 2);
    _Float16* WTe = (_Float16*)alloc((size_t)DIM * DIM * 2);
    float* ft = (float*)alloc((size_t)N_NODES * DIM * 4);
    _Float16* ftp = (_Float16*)alloc((size_t)N_EDGES * DIM * 2);
    float* a_ws = (float*)alloc((size_t)N_EDGES * H_HEADS * 4);
    unsigned int* counts = (unsigned int*)alloc((size_t)(N_NODES + 1) * 4);
    unsigned int* cursor = (unsigned int*)alloc((size_t)N_NODES * 4);
    int* esort = (int*)alloc((size_t)N_EDGES * 4);

    hipMemsetAsync(counts, 0, (size_t)(N_NODES + 1) * 4, stream);
    k_init_hist<<<(N_EDGES + 255) / 256, 256, 0, stream>>>(Wn, We, WTn, WTe, dst, counts);
    k_scan<<<1, 1024, 0, stream>>>(counts, cursor);
    k_scatter<<<(N_EDGES + 255) / 256, 256, 0, stream>>>(dst, cursor, esort);
    k_gemm_node<<<(N_NODES + 63) / 64, 256, 0, stream>>>(nfeat, WTn, ft, N_NODES);
    k_gemm_edge<<<N_EDGES / 64, 512, 0, stream>>>(efeat, WTe, ft, src, dst, esort, ftp, a_ws);
    k_agg<<<N_NODES / 4, 256, 0, stream>>>(counts, a_ws, ftp, out);
}